// Round 6
// baseline (166.259 us; speedup 1.0000x reference)
//
#include <hip/hip_runtime.h>
#include <hip/hip_fp16.h>

#define N_NODES 50000
#define N_EDGES 800000
#define D_IN 64
#define MAXD 64
#define BSHIFT 7                       // 128 nodes per bucket
#define BNODES 128
#define NBUCKET 391                    // ceil(50000/128)
#define NSCB 64                        // hist/scatter blocks
#define EPB (N_EDGES / NSCB)           // 12500 edges per hist/scatter block
#define NENT (NBUCKET * NSCB)          // 25024 (bucket-major)
#define LD4(p) (*(const float4*)(p))

// ---- K0: node linears: xw1n = x@w1n ; xr1b = x@w1r + b1 (fp16 out) ----
__global__ __launch_bounds__(256) void k_lin1(
        const float* __restrict__ x,
        const float* __restrict__ w1n, const float* __restrict__ w1r,
        const float* __restrict__ b1,
        __half* __restrict__ xw1n, __half* __restrict__ xr1b) {
    __shared__ float wn[1024], wr[1024], bs[16];
    for (int i = threadIdx.x; i < 1024; i += 256) { wn[i] = w1n[i]; wr[i] = w1r[i]; }
    if (threadIdx.x < 16) bs[threadIdx.x] = b1[threadIdx.x];
    __syncthreads();
    const int t = blockIdx.x * 256 + threadIdx.x;   // 800000 threads exactly
    const int node = t >> 4, f = t & 15;
    const float* xr = x + node * D_IN;
    float an = 0.f, ar = bs[f];
#pragma unroll
    for (int k = 0; k < D_IN; ++k) {
        float xv = xr[k];
        an += xv * wn[k * 16 + f];
        ar += xv * wr[k * 16 + f];
    }
    xw1n[t] = __float2half(an);
    xr1b[t] = __float2half(ar);
}

// ---- K1: per-block bucket histogram ----
__global__ __launch_bounds__(256) void k_hist(const int* __restrict__ dst,
                                              int* __restrict__ ghist) {
    __shared__ int lh[NBUCKET];
    for (int i = threadIdx.x; i < NBUCKET; i += 256) lh[i] = 0;
    __syncthreads();
    const int base = blockIdx.x * EPB;
    for (int i = threadIdx.x; i < EPB; i += 256)
        atomicAdd(&lh[dst[base + i] >> BSHIFT], 1);
    __syncthreads();
    for (int i = threadIdx.x; i < NBUCKET; i += 256)
        ghist[i * NSCB + blockIdx.x] = lh[i];        // bucket-major
}

// ---- K2: exclusive scan of ghist (one block) + bucket starts ----
__global__ __launch_bounds__(256) void k_scan(const int* __restrict__ ghist,
                                              int* __restrict__ gscan,
                                              int* __restrict__ bucketStart) {
    __shared__ int s[256];
    const int t = threadIdx.x;
    const int PER = (NENT + 255) / 256;              // 98
    const int lo = t * PER, hi = min(lo + PER, NENT);
    int sum = 0;
    for (int i = lo; i < hi; ++i) sum += ghist[i];
    s[t] = sum;
    __syncthreads();
    for (int d = 1; d < 256; d <<= 1) {
        int v = (t >= d) ? s[t - d] : 0;
        __syncthreads();
        s[t] += v;
        __syncthreads();
    }
    int run = s[t] - sum;                            // exclusive
    for (int i = lo; i < hi; ++i) {
        int v = ghist[i];
        gscan[i] = run;
        if ((i & (NSCB - 1)) == 0) bucketStart[i >> 6] = run;
        run += v;
    }
    if (t == 0) bucketStart[NBUCKET] = N_EDGES;
}

// ---- K3: scatter edges into bucket-grouped staging (packed u32) ----
__global__ __launch_bounds__(256) void k_scatter(const int* __restrict__ src,
                                                 const int* __restrict__ dst,
                                                 const int* __restrict__ gscan,
                                                 unsigned int* __restrict__ staging) {
    __shared__ int cur[NBUCKET];
    for (int i = threadIdx.x; i < NBUCKET; i += 256)
        cur[i] = gscan[i * NSCB + blockIdx.x];
    __syncthreads();
    const int base = blockIdx.x * EPB;
    for (int i = threadIdx.x; i < EPB; i += 256) {
        int d = dst[base + i], s = src[base + i];
        int pos = atomicAdd(&cur[d >> BSHIFT], 1);
        staging[pos] = ((unsigned int)(d & (BNODES - 1)) << 16) | (unsigned int)s;
    }
}

// ---- K4: per-bucket padded-table build in LDS, coalesced write-out ----
__global__ __launch_bounds__(256) void k_build(const unsigned int* __restrict__ staging,
                                               const int* __restrict__ bucketStart,
                                               unsigned int* __restrict__ nbrU,
                                               int* __restrict__ deg) {
    __shared__ unsigned short ltbl[BNODES * MAXD];
    __shared__ int lcnt[BNODES];
    const int tid = threadIdx.x, b = blockIdx.x;
    if (tid < BNODES) lcnt[tid] = 0;
    __syncthreads();
    const int beg = bucketStart[b], end = bucketStart[b + 1];
    for (int i = beg + tid; i < end; i += 256) {
        unsigned int u = staging[i];
        int dl = u >> 16, s = u & 0xFFFF;
        int slot = atomicAdd(&lcnt[dl], 1);
        if (slot < MAXD) ltbl[(dl << 6) + slot] = (unsigned short)s;
    }
    __syncthreads();
    const int nbase = b << BSHIFT;
    // rows: 32 uints per node (64 ushorts), coalesced
    for (int i = tid; i < BNODES * 32; i += 256) {
        int nl = i >> 5, j = i & 31;
        int node = nbase + nl;
        if (node < N_NODES && 2 * j < lcnt[nl]) {
            unsigned int lo = ltbl[(nl << 6) + 2 * j];
            unsigned int hi = ltbl[(nl << 6) + 2 * j + 1];
            nbrU[(node << 5) + j] = lo | (hi << 16);
        }
    }
    if (tid < BNODES && nbase + tid < N_NODES) deg[nbase + tid] = lcnt[tid];
}

// ---- K5: h1 = relu(mean_nbrs(xw1n) + xr1b) ----
__global__ __launch_bounds__(256) void k_agg1(
        const __half* __restrict__ xw1n, const __half* __restrict__ xr1b,
        const int* __restrict__ deg, const unsigned short* __restrict__ nbr,
        __half* __restrict__ h1) {
    const int t = blockIdx.x * 256 + threadIdx.x;
    if (t >= N_NODES * 16) return;
    const int node = t >> 4, f = t & 15;
    int c = deg[node];
    float inv = c > 0 ? 1.f / (float)c : 1.f;
    int cc = c > MAXD ? MAXD : c;
    const unsigned short* np = nbr + (node << 6);
    float a0 = 0.f, a1 = 0.f;
    int j = 0;
    for (; j + 2 <= cc; j += 2) {
        int s0 = np[j], s1 = np[j + 1];
        a0 += __half2float(xw1n[(s0 << 4) + f]);
        a1 += __half2float(xw1n[(s1 << 4) + f]);
    }
    if (j < cc) a0 += __half2float(xw1n[(np[j] << 4) + f]);
    h1[t] = __float2half(fmaxf((a0 + a1) * inv + __half2float(xr1b[t]), 0.f));
}

// ---- K6 (k_head): inline agg2 gather + SAGE2 + MLP head ----
__global__ __launch_bounds__(256) void k_head(
        const __half* __restrict__ h1,
        const int* __restrict__ deg, const unsigned short* __restrict__ nbr,
        const float* __restrict__ w2n, const float* __restrict__ w2r,
        const float* __restrict__ b2,
        const float* __restrict__ fw1, const float* __restrict__ fb1,
        const float* __restrict__ fw2, const float* __restrict__ fb2,
        const float* __restrict__ fw3, const float* __restrict__ fb3,
        float* __restrict__ out) {
    __shared__ __align__(16) float s_w2n[512];
    __shared__ __align__(16) float s_w2r[512];
    __shared__ __align__(16) float s_fw1[2048];
    __shared__ __align__(16) float s_fw2[4 * 2056];   // [q][k][32] + pad 8
    __shared__ __align__(16) float s_fw3[256];
    __shared__ __align__(16) float s_b2[32];
    __shared__ __align__(16) float s_fb1[64];
    __shared__ __align__(16) float s_fb2[128];
    __shared__ float s_fb3[2];

    const int tid = threadIdx.x;
    for (int i = tid; i < 512; i += 256) { s_w2n[i] = w2n[i]; s_w2r[i] = w2r[i]; }
    for (int i = tid; i < 2048; i += 256) s_fw1[i] = fw1[i];
    for (int i = tid; i < 8192; i += 256) {
        int k = i >> 7, jj = i & 127;
        s_fw2[(jj >> 5) * 2056 + k * 32 + (jj & 31)] = fw2[i];
    }
    s_fw3[tid] = fw3[tid & 255];
    if (tid < 32) s_b2[tid] = b2[tid];
    if (tid < 64) s_fb1[tid] = fb1[tid];
    if (tid < 128) s_fb2[tid] = fb2[tid];
    if (tid < 2) s_fb3[tid] = fb3[tid];
    __syncthreads();

    const int nl = tid >> 2;             // node local 0..63
    const int q  = tid & 3;              // quarter lane
    const int node = blockIdx.x * 64 + nl;
    const int nodec = node < N_NODES ? node : (N_NODES - 1);
    const int qbase = (tid & 63) & ~3;   // quad base lane in wave

    // ---- agg2 gather: lane q accumulates h1 features q*4..q*4+3 ----
    float za[4];
    {
        int c = deg[nodec];
        float inv = c > 0 ? 1.f / (float)c : 1.f;
        int cc = c > MAXD ? MAXD : c;
        const unsigned short* np = nbr + (nodec << 6);
        float a0 = 0.f, a1 = 0.f, a2 = 0.f, a3 = 0.f;
        for (int j = 0; j < cc; ++j) {
            int s = np[j];                                   // quad broadcast
            const __half2* hp = (const __half2*)(h1 + (s << 4) + (q << 2));
            float2 v0 = __half22float2(hp[0]);
            float2 v1 = __half22float2(hp[1]);
            a0 += v0.x; a1 += v0.y; a2 += v1.x; a3 += v1.y;
        }
        za[0] = a0 * inv; za[1] = a1 * inv; za[2] = a2 * inv; za[3] = a3 * inv;
    }
    // own h1 slice
    float zh[4];
    {
        const __half2* hp = (const __half2*)(h1 + (nodec << 4) + (q << 2));
        float2 v0 = __half22float2(hp[0]), v1 = __half22float2(hp[1]);
        zh[0] = v0.x; zh[1] = v0.y; zh[2] = v1.x; zh[3] = v1.y;
    }

    // ---- h2 = relu(agg@w2n + h1@w2r + b2): f-slice 8 (f0 = q*8) ----
    float h2r[8];
    {
        const int f0 = q * 8;
        float4 accA = LD4(s_b2 + f0), accB = LD4(s_b2 + f0 + 4);
#pragma unroll
        for (int k = 0; k < 16; ++k) {
            int sl = qbase + (k >> 2);
            float zn = __shfl(za[k & 3], sl);
            float zr = __shfl(zh[k & 3], sl);
            float4 wnA = LD4(s_w2n + k * 32 + f0), wnB = LD4(s_w2n + k * 32 + f0 + 4);
            float4 wrA = LD4(s_w2r + k * 32 + f0), wrB = LD4(s_w2r + k * 32 + f0 + 4);
            accA.x += zn * wnA.x + zr * wrA.x;
            accA.y += zn * wnA.y + zr * wrA.y;
            accA.z += zn * wnA.z + zr * wrA.z;
            accA.w += zn * wnA.w + zr * wrA.w;
            accB.x += zn * wnB.x + zr * wrB.x;
            accB.y += zn * wnB.y + zr * wrB.y;
            accB.z += zn * wnB.z + zr * wrB.z;
            accB.w += zn * wnB.w + zr * wrB.w;
        }
        h2r[0] = fmaxf(accA.x, 0.f); h2r[1] = fmaxf(accA.y, 0.f);
        h2r[2] = fmaxf(accA.z, 0.f); h2r[3] = fmaxf(accA.w, 0.f);
        h2r[4] = fmaxf(accB.x, 0.f); h2r[5] = fmaxf(accB.y, 0.f);
        h2r[6] = fmaxf(accB.z, 0.f); h2r[7] = fmaxf(accB.w, 0.f);
    }

    // ---- h3 = relu(h2@fw1 + fb1): j-slice 16 (j0 = q*16) ----
    float h3r[16];
    {
        const int j0 = q * 16;
        float4 a0 = LD4(s_fb1 + j0 + 0), a1 = LD4(s_fb1 + j0 + 4);
        float4 a2 = LD4(s_fb1 + j0 + 8), a3 = LD4(s_fb1 + j0 + 12);
#pragma unroll
        for (int k = 0; k < 32; ++k) {
            float hk = __shfl(h2r[k & 7], qbase + (k >> 3));
            const float* wp = s_fw1 + k * 64 + j0;
            float4 w0 = LD4(wp + 0), w1 = LD4(wp + 4), w2 = LD4(wp + 8), w3 = LD4(wp + 12);
            a0.x += hk * w0.x; a0.y += hk * w0.y; a0.z += hk * w0.z; a0.w += hk * w0.w;
            a1.x += hk * w1.x; a1.y += hk * w1.y; a1.z += hk * w1.z; a1.w += hk * w1.w;
            a2.x += hk * w2.x; a2.y += hk * w2.y; a2.z += hk * w2.z; a2.w += hk * w2.w;
            a3.x += hk * w3.x; a3.y += hk * w3.y; a3.z += hk * w3.z; a3.w += hk * w3.w;
        }
        h3r[0]  = fmaxf(a0.x, 0.f); h3r[1]  = fmaxf(a0.y, 0.f);
        h3r[2]  = fmaxf(a0.z, 0.f); h3r[3]  = fmaxf(a0.w, 0.f);
        h3r[4]  = fmaxf(a1.x, 0.f); h3r[5]  = fmaxf(a1.y, 0.f);
        h3r[6]  = fmaxf(a1.z, 0.f); h3r[7]  = fmaxf(a1.w, 0.f);
        h3r[8]  = fmaxf(a2.x, 0.f); h3r[9]  = fmaxf(a2.y, 0.f);
        h3r[10] = fmaxf(a2.z, 0.f); h3r[11] = fmaxf(a2.w, 0.f);
        h3r[12] = fmaxf(a3.x, 0.f); h3r[13] = fmaxf(a3.y, 0.f);
        h3r[14] = fmaxf(a3.z, 0.f); h3r[15] = fmaxf(a3.w, 0.f);
    }

    // ---- h4 = relu(h3@fw2 + fb2), out = h4@fw3 + fb3: j-slice 32 ----
    {
        const int j0 = q * 32;
        float4 b0 = LD4(s_fb2 + j0 + 0),  b1v = LD4(s_fb2 + j0 + 4);
        float4 b2v = LD4(s_fb2 + j0 + 8), b3v = LD4(s_fb2 + j0 + 12);
        float4 b4v = LD4(s_fb2 + j0 + 16), b5v = LD4(s_fb2 + j0 + 20);
        float4 b6v = LD4(s_fb2 + j0 + 24), b7v = LD4(s_fb2 + j0 + 28);
        const float* wbase = s_fw2 + q * 2056;
#pragma unroll
        for (int k = 0; k < 64; ++k) {
            float hk = __shfl(h3r[k & 15], qbase + (k >> 4));
            const float* wp = wbase + k * 32;
            float4 w;
            w = LD4(wp + 0);  b0.x += hk * w.x; b0.y += hk * w.y; b0.z += hk * w.z; b0.w += hk * w.w;
            w = LD4(wp + 4);  b1v.x += hk * w.x; b1v.y += hk * w.y; b1v.z += hk * w.z; b1v.w += hk * w.w;
            w = LD4(wp + 8);  b2v.x += hk * w.x; b2v.y += hk * w.y; b2v.z += hk * w.z; b2v.w += hk * w.w;
            w = LD4(wp + 12); b3v.x += hk * w.x; b3v.y += hk * w.y; b3v.z += hk * w.z; b3v.w += hk * w.w;
            w = LD4(wp + 16); b4v.x += hk * w.x; b4v.y += hk * w.y; b4v.z += hk * w.z; b4v.w += hk * w.w;
            w = LD4(wp + 20); b5v.x += hk * w.x; b5v.y += hk * w.y; b5v.z += hk * w.z; b5v.w += hk * w.w;
            w = LD4(wp + 24); b6v.x += hk * w.x; b6v.y += hk * w.y; b6v.z += hk * w.z; b6v.w += hk * w.w;
            w = LD4(wp + 28); b7v.x += hk * w.x; b7v.y += hk * w.y; b7v.z += hk * w.z; b7v.w += hk * w.w;
        }
        float o0 = 0.f, o1 = 0.f;
        float4 f1, f2;
#define OUTSTEP(bb, boff)                                                    \
        f1 = LD4(s_fw3 + (j0 + boff) * 2);                                   \
        f2 = LD4(s_fw3 + (j0 + boff) * 2 + 4);                               \
        { float r0 = fmaxf(bb.x, 0.f), r1 = fmaxf(bb.y, 0.f),                \
                r2 = fmaxf(bb.z, 0.f), r3 = fmaxf(bb.w, 0.f);                \
          o0 += r0 * f1.x + r1 * f1.z + r2 * f2.x + r3 * f2.z;               \
          o1 += r0 * f1.y + r1 * f1.w + r2 * f2.y + r3 * f2.w; }
        OUTSTEP(b0, 0)   OUTSTEP(b1v, 4)  OUTSTEP(b2v, 8)   OUTSTEP(b3v, 12)
        OUTSTEP(b4v, 16) OUTSTEP(b5v, 20) OUTSTEP(b6v, 24)  OUTSTEP(b7v, 28)
#undef OUTSTEP
        o0 += __shfl_xor(o0, 1); o0 += __shfl_xor(o0, 2);
        o1 += __shfl_xor(o1, 1); o1 += __shfl_xor(o1, 2);
        if (q == 0 && node < N_NODES) {
            float2 r; r.x = o0 + s_fb3[0]; r.y = o1 + s_fb3[1];
            *(float2*)(out + node * 2) = r;
        }
    }
}

extern "C" void kernel_launch(void* const* d_in, const int* in_sizes, int n_in,
                              void* d_out, int out_size, void* d_ws, size_t ws_size,
                              hipStream_t stream) {
    const float* x   = (const float*)d_in[0];
    const int*   ei  = (const int*)d_in[1];
    const int*   src = ei;
    const int*   dst = ei + N_EDGES;
    const float* w1n = (const float*)d_in[2];
    const float* w1r = (const float*)d_in[3];
    const float* b1  = (const float*)d_in[4];
    const float* w2n = (const float*)d_in[5];
    const float* w2r = (const float*)d_in[6];
    const float* b2  = (const float*)d_in[7];
    const float* fw1 = (const float*)d_in[8];
    const float* fb1 = (const float*)d_in[9];
    const float* fw2 = (const float*)d_in[10];
    const float* fb2 = (const float*)d_in[11];
    const float* fw3 = (const float*)d_in[12];
    const float* fb3 = (const float*)d_in[13];
    float* out = (float*)d_out;

    // workspace layout (~15.2 MB)
    unsigned int*   nbrU        = (unsigned int*)d_ws;              // 50000*32 uints (6.4MB)
    int*            deg         = (int*)(nbrU + N_NODES * 32);      // 50000
    __half*         xw1n        = (__half*)(deg + N_NODES);         // 800000
    __half*         xr1b        = xw1n + N_EDGES;                   // 800000
    __half*         h1          = xr1b + N_EDGES;                   // 800000
    unsigned int*   staging     = (unsigned int*)(h1 + N_EDGES);    // 800000 (3.2MB)
    int*            ghist       = (int*)(staging + N_EDGES);        // 25024
    int*            gscan       = ghist + NENT;                     // 25024
    int*            bucketStart = gscan + NENT;                     // 392

    const unsigned short* nbr = (const unsigned short*)nbrU;

    k_lin1<<<N_EDGES / 256, 256, 0, stream>>>(x, w1n, w1r, b1, xw1n, xr1b);
    k_hist<<<NSCB, 256, 0, stream>>>(dst, ghist);
    k_scan<<<1, 256, 0, stream>>>(ghist, gscan, bucketStart);
    k_scatter<<<NSCB, 256, 0, stream>>>(src, dst, gscan, staging);
    k_build<<<NBUCKET, 256, 0, stream>>>(staging, bucketStart, nbrU, deg);
    k_agg1<<<(N_NODES * 16 + 255) / 256, 256, 0, stream>>>(xw1n, xr1b, deg, nbr, h1);
    k_head<<<(N_NODES + 63) / 64, 256, 0, stream>>>(h1, deg, nbr, w2n, w2r, b2,
                                                    fw1, fb1, fw2, fb2, fw3, fb3, out);
}